// Round 20
// baseline (133.544 us; speedup 1.0000x reference)
//
#include <hip/hip_runtime.h>

// RK4 Gray-Scott, y-march, static circular windows, packed-f32, f4 LDS,
// 4-slot / barrier-every-2 protocol (r14 base = 90.6us best). THIS ROUND,
// two zero-VALU-cost LDS reductions:
//  1) +-2-lane neighbor reads fetch ONLY the 2 used dwords (u.y+v.w left,
//     u.x+v.z right) -> compiler emits ds_read2_b32 (8B vs 16B). Per-stage
//     exchange bytes 64 -> 48.
//  2) ALL active stages' neighbor reads hoisted to step top (safe: reads hit
//     slot (c+2)&3; every write this step goes to slot c&3 -> disjoint),
//     so the 4 serial read->use latency chains overlap into one batch.
// Everything else byte-identical to r14.
// RK fold: AC = 4*Y1 + 8*Y2 - 4*u0 (row yL-6); out = (AC[lag6]+4*Y3c+k4)/12.

typedef float f2 __attribute__((ext_vector_type(2)));
typedef float f4 __attribute__((ext_vector_type(4)));

#define HROWS 64
#define NT    512
#define STEPS (HROWS + 24)   // 88

#define W0 ((-980.0f / 1e-4f) / 180.0f)
#define W1 ((  270.0f / 1e-4f) / 180.0f)
#define W2 (( -27.0f / 1e-4f) / 180.0f)
#define W3 ((   2.0f / 1e-4f) / 180.0f)

__device__ __forceinline__ f2 sp(float s) { f2 r; r.x = s; r.y = s; return r; }
__device__ __forceinline__ f2 pfma(float s, f2 a, f2 c) {
    return __builtin_elementwise_fma(sp(s), a, c);
}

// Neighbor bundle for one stage (loaded at step top).
struct Nb { f4 m1d, p1d; float am3u, am3v, bp3u, bp3v; };

__device__ __forceinline__ Nb ldnb(const f4* __restrict__ Ls,
                                   int xm2, int xm1, int xp1, int xp2) {
    Nb n;
    n.m1d = Ls[xm1];                     // cols a-2,a-1 (u pair + v pair)
    n.p1d = Ls[xp1];                     // cols a+2,a+3
    const float* f = (const float*)Ls;
    n.am3u = f[4 * xm2 + 1];             // col a-3, u  (ds_read2_b32 pair)
    n.am3v = f[4 * xm2 + 3];             // col a-3, v
    n.bp3u = f[4 * xp2 + 0];             // col b+3, u  (ds_read2_b32 pair)
    n.bp3v = f[4 * xp2 + 2];             // col b+3, v
    return n;
}

// 13-pt Laplacian, packed over 2 cols (a=2l, b=2l+1).
// w0..w6 = vertical rows lag6..lag0 (center w3); m1={a-2,a-1}, p1={a+2,a+3},
// am3 = col a-3, bp3 = col b+3.
__device__ __forceinline__ void evalp7x(f2 w0, f2 w1, f2 w2, f2 w3, f2 w4,
                                        f2 w5, f2 w6, f2 m1, f2 p1,
                                        float am3, float bp3,
                                        f2& lap, f2& ctr)
{
    ctr = w3;
    f2 vp = pfma(W1, w2 + w4, pfma(W2, w1 + w5, sp(W3) * (w0 + w6)));
    f2 m1q; m1q.x = m1.y;  m1q.y = ctr.x;   // {a-1, b-1}
    f2 p1q; p1q.x = ctr.y; p1q.y = p1.x;    // {a+1, b+1}
    f2 m3q; m3q.x = am3;   m3q.y = m1.x;    // {a-3, b-3}
    f2 p3q; p3q.x = p1.y;  p3q.y = bp3;     // {a+3, b+3}
    f2 hp = pfma(W1, m1q + p1q, pfma(W2, m1 + p1, sp(W3) * (m3q + p3q)));
    lap = pfma(W0, ctr, hp + vp);
}

#define ULD(n) __builtin_shufflevector((n).m1d, (n).m1d, 0, 1)
#define VLD(n) __builtin_shufflevector((n).m1d, (n).m1d, 2, 3)
#define URD(n) __builtin_shufflevector((n).p1d, (n).p1d, 0, 1)
#define VRD(n) __builtin_shufflevector((n).p1d, (n).p1d, 2, 3)

__global__ __launch_bounds__(NT, 1) void rcnn_rk4_march(
    const float* __restrict__ h,
    const float* __restrict__ pCA, const float* __restrict__ pCB,
    const float* __restrict__ pNA, const float* __restrict__ pNB,
    const float* __restrict__ pf,  const float* __restrict__ pk,
    float* __restrict__ out)
{
    __shared__ f4 S[4][4][NT];   // [stage][slot][col] = 128 KiB

    const int tid = threadIdx.x;
    const int Y0  = blockIdx.x * HROWS;
    const int b   = blockIdx.z;

    const float NA = pNA[0], NB = pNB[0];
    const float ff = pf[0];
    const float kpf = pk[0] + pf[0];
    const float mu_u = 4e-5f / (1.0f + expf(-pCA[0]));
    const float mu_v = 4e-5f / (1.0f + expf(-pCB[0]));

    const size_t baseU = (size_t)b * 2u * 1048576u;
    const size_t baseV = baseU + 1048576u;
    const float* hU = h + baseU + 2 * tid;
    const float* hV = h + baseV + 2 * tid;
    float* oU = out + baseU + 2 * tid;
    float* oV = out + baseV + 2 * tid;

    const int xm2 = (tid - 2) & 511;
    const int xm1 = (tid - 1) & 511;
    const int xp1 = (tid + 1) & 511;
    const int xp2 = (tid + 2) & 511;

    f2 Uu[8], Uv[8], Du[8], Dv[8];
    f2 Y1u[8], Y1v[8], Y2u[8], Y2v[8], Y3u[8], Y3v[8];
    f2 ACu[8], ACv[8];

    const f2 z = sp(0.0f);
    #pragma unroll
    for (int j = 0; j < 8; ++j) {
        Uu[j]=z; Uv[j]=z; Du[j]=z; Dv[j]=z;
        Y1u[j]=z; Y1v[j]=z; Y2u[j]=z; Y2v[j]=z; Y3u[j]=z; Y3v[j]=z;
        ACu[j]=z; ACv[j]=z;
    }

    // 2-deep prefetch: pA = even steps, pB = odd steps
    f2 pAu, pAv, pBu, pBv;
    {
        int r0 = (Y0 - 12) & 1023;
        int r1 = (Y0 - 11) & 1023;
        pAu = *(const f2*)(hU + (size_t)r0 * 1024);
        pAv = *(const f2*)(hV + (size_t)r0 * 1024);
        pBu = *(const f2*)(hU + (size_t)r1 * 1024);
        pBv = *(const f2*)(hV + (size_t)r1 * 1024);
    }

// Writes: stage row LAG-1 phase ((c)+7)&7 -> slot (c)&3.
// Reads:  slot ((c)+2)&3 (written at t-2 => that stage row at lag 3 now).
// Barrier after odd c only (4-slot algebra, r13/r14 proven).
#define STEP(c, G1, G2, G3, G4, tb_)                                          \
  {                                                                           \
    const int t_ = (tb_) + (c);                                               \
    /* ---- hoisted neighbor reads for all active stages ---- */              \
    Nb n1, n2, n3, n4;                                                        \
    if (G1) n1 = ldnb(&S[0][((c)+2)&3][0], xm2, xm1, xp1, xp2);               \
    if (G2) n2 = ldnb(&S[1][((c)+2)&3][0], xm2, xm1, xp1, xp2);               \
    if (G3) n3 = ldnb(&S[2][((c)+2)&3][0], xm2, xm1, xp1, xp2);               \
    if (G4) n4 = ldnb(&S[3][((c)+2)&3][0], xm2, xm1, xp1, xp2);               \
    /* delay copy: D[c] = u0 lag 5 (phase (c+3)&7) */                         \
    Du[(c)&7] = Uu[((c)+3)&7]; Dv[(c)&7] = Uv[((c)+3)&7];                     \
    /* consume prefetch: u0 row yL */                                         \
    Uu[(c)&7] = ((c)&1) ? pBu : pAu;                                          \
    Uv[(c)&7] = ((c)&1) ? pBv : pAv;                                          \
    /* u0 row yL-1 (lag 1, phase (c+7)&7) -> slot c&3 */                      \
    S[0][(c)&3][tid] = __builtin_shufflevector(Uu[((c)+7)&7], Uv[((c)+7)&7],  \
                                               0, 1, 2, 3);                   \
    /* issue prefetch for row yL+2 */                                         \
    {                                                                         \
      int yn = (Y0 - 10 + t_) & 1023;                                         \
      f2 au = *(const f2*)(hU + (size_t)yn * 1024);                           \
      f2 av = *(const f2*)(hV + (size_t)yn * 1024);                           \
      if ((c)&1) { pBu = au; pBv = av; } else { pAu = au; pAv = av; }         \
    }                                                                         \
    if (G1) { /* k1 on u0, row yL-3 */                                        \
      f2 lU, cU, lV, cV;                                                      \
      evalp7x(Uu[((c)+2)&7], Uu[((c)+3)&7], Uu[((c)+4)&7], Uu[((c)+5)&7],     \
              Uu[((c)+6)&7], Uu[((c)+7)&7], Uu[(c)&7],                        \
              ULD(n1), URD(n1), n1.am3u, n1.bp3u, lU, cU);                    \
      evalp7x(Uv[((c)+2)&7], Uv[((c)+3)&7], Uv[((c)+4)&7], Uv[((c)+5)&7],     \
              Uv[((c)+6)&7], Uv[((c)+7)&7], Uv[(c)&7],                        \
              VLD(n1), VRD(n1), n1.am3v, n1.bp3v, lV, cV);                    \
      f2 uv2 = cU * cV * cV;                                                  \
      f2 kU = pfma(mu_u, lU, pfma(NA, uv2, pfma(-ff, cU, sp(ff))));           \
      f2 kV = pfma(mu_v, lV, pfma(NB, uv2, sp(-kpf) * cV));                   \
      Y1u[(c)&7] = pfma(0.25f, kU, cU);                                       \
      Y1v[(c)&7] = pfma(0.25f, kV, cV);                                       \
      S[1][(c)&3][tid] = __builtin_shufflevector(Y1u[((c)+7)&7],              \
                                                 Y1v[((c)+7)&7], 0, 1, 2, 3); \
    }                                                                         \
    if (G2) { /* k2 on Y1, row yL-6 ; fold AC */                              \
      f2 lU, cU, lV, cV;                                                      \
      evalp7x(Y1u[((c)+2)&7], Y1u[((c)+3)&7], Y1u[((c)+4)&7], Y1u[((c)+5)&7], \
              Y1u[((c)+6)&7], Y1u[((c)+7)&7], Y1u[(c)&7],                     \
              ULD(n2), URD(n2), n2.am3u, n2.bp3u, lU, cU);                    \
      evalp7x(Y1v[((c)+2)&7], Y1v[((c)+3)&7], Y1v[((c)+4)&7], Y1v[((c)+5)&7], \
              Y1v[((c)+6)&7], Y1v[((c)+7)&7], Y1v[(c)&7],                     \
              VLD(n2), VRD(n2), n2.am3v, n2.bp3v, lV, cV);                    \
      f2 uv2 = cU * cV * cV;                                                  \
      f2 kU = pfma(mu_u, lU, pfma(NA, uv2, pfma(-ff, cU, sp(ff))));           \
      f2 kV = pfma(mu_v, lV, pfma(NB, uv2, sp(-kpf) * cV));                   \
      f2 bu = Du[((c)+7)&7], bv = Dv[((c)+7)&7];   /* u0 lag 6 */             \
      f2 nu = pfma(0.25f, kU, bu), nv = pfma(0.25f, kV, bv);                  \
      Y2u[(c)&7] = nu; Y2v[(c)&7] = nv;                                       \
      f2 aU = pfma(4.0f, Y1u[((c)+5)&7], sp(8.0f) * nu);                      \
      f2 aV = pfma(4.0f, Y1v[((c)+5)&7], sp(8.0f) * nv);                      \
      ACu[(c)&7] = pfma(-4.0f, bu, aU);                                       \
      ACv[(c)&7] = pfma(-4.0f, bv, aV);                                       \
      S[2][(c)&3][tid] = __builtin_shufflevector(Y2u[((c)+7)&7],              \
                                                 Y2v[((c)+7)&7], 0, 1, 2, 3); \
    }                                                                         \
    if (G3) { /* k3 on Y2, row yL-9 */                                        \
      f2 lU, cU, lV, cV;                                                      \
      evalp7x(Y2u[((c)+2)&7], Y2u[((c)+3)&7], Y2u[((c)+4)&7], Y2u[((c)+5)&7], \
              Y2u[((c)+6)&7], Y2u[((c)+7)&7], Y2u[(c)&7],                     \
              ULD(n3), URD(n3), n3.am3u, n3.bp3u, lU, cU);                    \
      evalp7x(Y2v[((c)+2)&7], Y2v[((c)+3)&7], Y2v[((c)+4)&7], Y2v[((c)+5)&7], \
              Y2v[((c)+6)&7], Y2v[((c)+7)&7], Y2v[(c)&7],                     \
              VLD(n3), VRD(n3), n3.am3v, n3.bp3v, lV, cV);                    \
      f2 uv2 = cU * cV * cV;                                                  \
      f2 kU = pfma(mu_u, lU, pfma(NA, uv2, pfma(-ff, cU, sp(ff))));           \
      f2 kV = pfma(mu_v, lV, pfma(NB, uv2, sp(-kpf) * cV));                   \
      Y3u[(c)&7] = pfma(0.5f, kU, Du[((c)+4)&7]);   /* u0 lag 9 */            \
      Y3v[(c)&7] = pfma(0.5f, kV, Dv[((c)+4)&7]);                             \
      S[3][(c)&3][tid] = __builtin_shufflevector(Y3u[((c)+7)&7],              \
                                                 Y3v[((c)+7)&7], 0, 1, 2, 3); \
    }                                                                         \
    if (G4) { /* k4 on Y3, row yL-12 ; write output */                        \
      f2 lU, cU4, lV, cV4;                                                    \
      evalp7x(Y3u[((c)+2)&7], Y3u[((c)+3)&7], Y3u[((c)+4)&7], Y3u[((c)+5)&7], \
              Y3u[((c)+6)&7], Y3u[((c)+7)&7], Y3u[(c)&7],                     \
              ULD(n4), URD(n4), n4.am3u, n4.bp3u, lU, cU4);                   \
      evalp7x(Y3v[((c)+2)&7], Y3v[((c)+3)&7], Y3v[((c)+4)&7], Y3v[((c)+5)&7], \
              Y3v[((c)+6)&7], Y3v[((c)+7)&7], Y3v[(c)&7],                     \
              VLD(n4), VRD(n4), n4.am3v, n4.bp3v, lV, cV4);                   \
      f2 uv2 = cU4 * cV4 * cV4;                                               \
      f2 kU = pfma(mu_u, lU, pfma(NA, uv2, pfma(-ff, cU4, sp(ff))));          \
      f2 kV = pfma(mu_v, lV, pfma(NB, uv2, sp(-kpf) * cV4));                  \
      f2 sU = pfma(4.0f, cU4, kU) + ACu[((c)+2)&7];   /* AC lag 6 */          \
      f2 sV = pfma(4.0f, cV4, kV) + ACv[((c)+2)&7];                           \
      f2 oUq = sp(1.0f / 12.0f) * sU;                                         \
      f2 oVq = sp(1.0f / 12.0f) * sV;                                         \
      int yS = Y0 + t_ - 24;                                                  \
      *(f2*)(oU + (size_t)yS * 1024) = oUq;                                   \
      *(f2*)(oV + (size_t)yS * 1024) = oVq;                                   \
    }                                                                         \
    if ((c) & 1) {                                                            \
      asm volatile("s_waitcnt lgkmcnt(0)" ::: "memory");                      \
      __builtin_amdgcn_s_barrier();                                           \
    }                                                                         \
  }

    // warmup: compile-time guards per 8-step block
    STEP(0,0,0,0,0, 0) STEP(1,0,0,0,0, 0) STEP(2,0,0,0,0, 0) STEP(3,0,0,0,0, 0)
    STEP(4,0,0,0,0, 0) STEP(5,0,0,0,0, 0) STEP(6,1,0,0,0, 0) STEP(7,1,0,0,0, 0)

    STEP(0,1,0,0,0, 8) STEP(1,1,0,0,0, 8) STEP(2,1,0,0,0, 8) STEP(3,1,0,0,0, 8)
    STEP(4,1,1,0,0, 8) STEP(5,1,1,0,0, 8) STEP(6,1,1,0,0, 8) STEP(7,1,1,0,0, 8)

    STEP(0,1,1,0,0,16) STEP(1,1,1,0,0,16) STEP(2,1,1,1,0,16) STEP(3,1,1,1,0,16)
    STEP(4,1,1,1,0,16) STEP(5,1,1,1,0,16) STEP(6,1,1,1,0,16) STEP(7,1,1,1,0,16)

    #pragma unroll 1
    for (int tb = 24; tb < STEPS; tb += 8) {
        STEP(0,1,1,1,1,tb) STEP(1,1,1,1,1,tb) STEP(2,1,1,1,1,tb) STEP(3,1,1,1,1,tb)
        STEP(4,1,1,1,1,tb) STEP(5,1,1,1,1,tb) STEP(6,1,1,1,1,tb) STEP(7,1,1,1,1,tb)
    }
#undef STEP
}

extern "C" void kernel_launch(void* const* d_in, const int* in_sizes, int n_in,
                              void* d_out, int out_size, void* d_ws, size_t ws_size,
                              hipStream_t stream) {
    const float* h   = (const float*)d_in[0];
    const float* pCA = (const float*)d_in[1];
    const float* pCB = (const float*)d_in[2];
    const float* pNA = (const float*)d_in[3];
    const float* pNB = (const float*)d_in[4];
    const float* pf  = (const float*)d_in[5];
    const float* pk  = (const float*)d_in[6];
    float* outp = (float*)d_out;

    dim3 grid(1024 / HROWS, 1, 16);   // 16 strips x 16 batches = 256 blocks
    dim3 block(NT);
    rcnn_rk4_march<<<grid, block, 0, stream>>>(h, pCA, pCB, pNA, pNB, pf, pk, outp);
}

// Round 21
// 90.309 us; speedup vs baseline: 1.4788x; 1.4788x over previous
//
#include <hip/hip_runtime.h>

// RK4 Gray-Scott, y-march, STATIC circular register windows, packed-f32,
// f4-packed LDS, 4-slot / barrier-every-2-steps protocol.
// == ROUND-14 KERNEL RESTORED VERBATIM (best measured: 90.6 us) ==
// Six attempted improvements on the LDS exchange (DPP, 4-col march, global
// neighbors, bf16 packing, pair-coop reads, read2+hoist) all regressed;
// this configuration is the empirical optimum of the structure.
// Block = 512 threads = full 1024-wide row (2 cols/thread via f2, wrap &511).
// LDS: S[stage][slot][col] f4 {u.a,u.b,v.a,v.b}. Stage rows are written from
// the stage's LAG-1 phase at step t into slot t&3; consumers read slot
// (t+2)&3 (= written at t-2, row lag matches: (yL(t-2))-1 = yL(t)-3).
// Slot distinctness within an even-aligned step pair {c,c+1}: writes c&3,
// (c+1)&3; reads (c+2)&3, (c+3)&3 -> all four distinct -> NO barrier inside
// the pair; one lgkmcnt(0)+s_barrier after odd steps covers cross-pair
// hazards.
// RK fold: AC = 4*Y1 + 8*Y2 - 4*u0 (row yL-6); out = (AC[lag6]+4*Y3c+k4)/12.

typedef float f2 __attribute__((ext_vector_type(2)));
typedef float f4 __attribute__((ext_vector_type(4)));

#define HROWS 64
#define NT    512
#define STEPS (HROWS + 24)   // 88

#define W0 ((-980.0f / 1e-4f) / 180.0f)
#define W1 ((  270.0f / 1e-4f) / 180.0f)
#define W2 (( -27.0f / 1e-4f) / 180.0f)
#define W3 ((   2.0f / 1e-4f) / 180.0f)

__device__ __forceinline__ f2 sp(float s) { f2 r; r.x = s; r.y = s; return r; }
__device__ __forceinline__ f2 pfma(float s, f2 a, f2 c) {
    return __builtin_elementwise_fma(sp(s), a, c);
}
__device__ __forceinline__ f2 lo2(f4 a) { return __builtin_shufflevector(a, a, 0, 1); }
__device__ __forceinline__ f2 hi2(f4 a) { return __builtin_shufflevector(a, a, 2, 3); }
__device__ __forceinline__ f4 cat(f2 a, f2 b) { return __builtin_shufflevector(a, b, 0, 1, 2, 3); }

struct Hq  { f2 m2, m1, p1, p2; };
struct Hq4 { f4 m2, m1, p1, p2; };

__device__ __forceinline__ Hq4 rdq4(const f4* __restrict__ L,
                                    int xm2, int xm1, int xp1, int xp2) {
    Hq4 q;
    q.m2 = L[xm2]; q.m1 = L[xm1]; q.p1 = L[xp1]; q.p2 = L[xp2];
    return q;
}

// 13-pt Laplacian, packed over 2 cols. w0..w6 = vertical rows (center w3).
__device__ __forceinline__ void evalp7(f2 w0, f2 w1, f2 w2, f2 w3, f2 w4,
                                       f2 w5, f2 w6, const Hq& q,
                                       f2& lap, f2& ctr)
{
    ctr = w3;
    f2 vp = pfma(W1, w2 + w4, pfma(W2, w1 + w5, sp(W3) * (w0 + w6)));
    f2 m1 = __builtin_shufflevector(q.m1, ctr, 1, 2);   // {a-1, b-1}
    f2 p1 = __builtin_shufflevector(ctr, q.p1, 1, 2);   // {a+1, b+1}
    f2 m3 = __builtin_shufflevector(q.m2, q.m1, 1, 2);  // {a-3, b-3}
    f2 p3 = __builtin_shufflevector(q.p1, q.p2, 1, 2);  // {a+3, b+3}
    f2 hp = pfma(W1, m1 + p1, pfma(W2, q.m1 + q.p1, sp(W3) * (m3 + p3)));
    lap = pfma(W0, ctr, hp + vp);
}

__global__ __launch_bounds__(NT, 1) void rcnn_rk4_march(
    const float* __restrict__ h,
    const float* __restrict__ pCA, const float* __restrict__ pCB,
    const float* __restrict__ pNA, const float* __restrict__ pNB,
    const float* __restrict__ pf,  const float* __restrict__ pk,
    float* __restrict__ out)
{
    __shared__ f4 S[4][4][NT];   // [stage][slot][col] = 128 KiB

    const int tid = threadIdx.x;
    const int Y0  = blockIdx.x * HROWS;
    const int b   = blockIdx.z;

    const float NA = pNA[0], NB = pNB[0];
    const float ff = pf[0];
    const float kpf = pk[0] + pf[0];
    const float mu_u = 4e-5f / (1.0f + expf(-pCA[0]));
    const float mu_v = 4e-5f / (1.0f + expf(-pCB[0]));

    const size_t baseU = (size_t)b * 2u * 1048576u;
    const size_t baseV = baseU + 1048576u;
    const float* hU = h + baseU + 2 * tid;
    const float* hV = h + baseV + 2 * tid;
    float* oU = out + baseU + 2 * tid;
    float* oV = out + baseV + 2 * tid;

    const int xm2 = (tid - 2) & 511;
    const int xm1 = (tid - 1) & 511;
    const int xp1 = (tid + 1) & 511;
    const int xp2 = (tid + 2) & 511;

    f2 Uu[8], Uv[8], Du[8], Dv[8];
    f2 Y1u[8], Y1v[8], Y2u[8], Y2v[8], Y3u[8], Y3v[8];
    f2 ACu[8], ACv[8];

    const f2 z = sp(0.0f);
    #pragma unroll
    for (int j = 0; j < 8; ++j) {
        Uu[j]=z; Uv[j]=z; Du[j]=z; Dv[j]=z;
        Y1u[j]=z; Y1v[j]=z; Y2u[j]=z; Y2v[j]=z; Y3u[j]=z; Y3v[j]=z;
        ACu[j]=z; ACv[j]=z;
    }

    // 2-deep prefetch: pA = even steps, pB = odd steps
    f2 pAu, pAv, pBu, pBv;
    {
        int r0 = (Y0 - 12) & 1023;
        int r1 = (Y0 - 11) & 1023;
        pAu = *(const f2*)(hU + (size_t)r0 * 1024);
        pAv = *(const f2*)(hV + (size_t)r0 * 1024);
        pBu = *(const f2*)(hU + (size_t)r1 * 1024);
        pBv = *(const f2*)(hV + (size_t)r1 * 1024);
    }

// Writes: stage row LAG-1 phase ((c)+7)&7 -> slot (c)&3.
// Reads:  slot ((c)+2)&3 (written at t-2; contains the stage's row at
//         consumer-lag 3, since (lag-1 at t-2) == (lag-3 at t)).
// Barrier: only after odd c.
#define STEP(c, G1, G2, G3, G4, tb_)                                          \
  {                                                                           \
    const int t_ = (tb_) + (c);                                               \
    /* delay copy: D[c] = u0 lag 5 (phase (c+3)&7) */                         \
    Du[(c)&7] = Uu[((c)+3)&7]; Dv[(c)&7] = Uv[((c)+3)&7];                     \
    /* consume prefetch: u0 row yL */                                         \
    Uu[(c)&7] = ((c)&1) ? pBu : pAu;                                          \
    Uv[(c)&7] = ((c)&1) ? pBv : pAv;                                          \
    /* u0 row yL-1 (lag 1, phase (c+7)&7) -> slot c&3 */                      \
    S[0][(c)&3][tid] = cat(Uu[((c)+7)&7], Uv[((c)+7)&7]);                     \
    /* issue prefetch for row yL+2 */                                         \
    {                                                                         \
      int yn = (Y0 - 10 + t_) & 1023;                                         \
      f2 au = *(const f2*)(hU + (size_t)yn * 1024);                           \
      f2 av = *(const f2*)(hV + (size_t)yn * 1024);                           \
      if ((c)&1) { pBu = au; pBv = av; } else { pAu = au; pAv = av; }         \
    }                                                                         \
    if (G1) { /* k1 on u0, row yL-3 */                                        \
      Hq4 q = rdq4(&S[0][((c)+2)&3][0], xm2, xm1, xp1, xp2);                  \
      Hq qu = { lo2(q.m2), lo2(q.m1), lo2(q.p1), lo2(q.p2) };                 \
      Hq qv = { hi2(q.m2), hi2(q.m1), hi2(q.p1), hi2(q.p2) };                 \
      f2 lU, cU, lV, cV;                                                      \
      evalp7(Uu[((c)+2)&7], Uu[((c)+3)&7], Uu[((c)+4)&7], Uu[((c)+5)&7],      \
             Uu[((c)+6)&7], Uu[((c)+7)&7], Uu[(c)&7], qu, lU, cU);            \
      evalp7(Uv[((c)+2)&7], Uv[((c)+3)&7], Uv[((c)+4)&7], Uv[((c)+5)&7],      \
             Uv[((c)+6)&7], Uv[((c)+7)&7], Uv[(c)&7], qv, lV, cV);            \
      f2 uv2 = cU * cV * cV;                                                  \
      f2 kU = pfma(mu_u, lU, pfma(NA, uv2, pfma(-ff, cU, sp(ff))));           \
      f2 kV = pfma(mu_v, lV, pfma(NB, uv2, sp(-kpf) * cV));                   \
      Y1u[(c)&7] = pfma(0.25f, kU, cU);                                       \
      Y1v[(c)&7] = pfma(0.25f, kV, cV);                                       \
      S[1][(c)&3][tid] = cat(Y1u[((c)+7)&7], Y1v[((c)+7)&7]);                 \
    }                                                                         \
    if (G2) { /* k2 on Y1, row yL-6 ; fold AC */                              \
      Hq4 q = rdq4(&S[1][((c)+2)&3][0], xm2, xm1, xp1, xp2);                  \
      Hq qu = { lo2(q.m2), lo2(q.m1), lo2(q.p1), lo2(q.p2) };                 \
      Hq qv = { hi2(q.m2), hi2(q.m1), hi2(q.p1), hi2(q.p2) };                 \
      f2 lU, cU, lV, cV;                                                      \
      evalp7(Y1u[((c)+2)&7], Y1u[((c)+3)&7], Y1u[((c)+4)&7], Y1u[((c)+5)&7],  \
             Y1u[((c)+6)&7], Y1u[((c)+7)&7], Y1u[(c)&7], qu, lU, cU);         \
      evalp7(Y1v[((c)+2)&7], Y1v[((c)+3)&7], Y1v[((c)+4)&7], Y1v[((c)+5)&7],  \
             Y1v[((c)+6)&7], Y1v[((c)+7)&7], Y1v[(c)&7], qv, lV, cV);         \
      f2 uv2 = cU * cV * cV;                                                  \
      f2 kU = pfma(mu_u, lU, pfma(NA, uv2, pfma(-ff, cU, sp(ff))));           \
      f2 kV = pfma(mu_v, lV, pfma(NB, uv2, sp(-kpf) * cV));                   \
      f2 bu = Du[((c)+7)&7], bv = Dv[((c)+7)&7];   /* u0 lag 6 */             \
      f2 nu = pfma(0.25f, kU, bu), nv = pfma(0.25f, kV, bv);                  \
      Y2u[(c)&7] = nu; Y2v[(c)&7] = nv;                                       \
      f2 aU = pfma(4.0f, Y1u[((c)+5)&7], sp(8.0f) * nu);                      \
      f2 aV = pfma(4.0f, Y1v[((c)+5)&7], sp(8.0f) * nv);                      \
      ACu[(c)&7] = pfma(-4.0f, bu, aU);                                       \
      ACv[(c)&7] = pfma(-4.0f, bv, aV);                                       \
      S[2][(c)&3][tid] = cat(Y2u[((c)+7)&7], Y2v[((c)+7)&7]);                 \
    }                                                                         \
    if (G3) { /* k3 on Y2, row yL-9 */                                        \
      Hq4 q = rdq4(&S[2][((c)+2)&3][0], xm2, xm1, xp1, xp2);                  \
      Hq qu = { lo2(q.m2), lo2(q.m1), lo2(q.p1), lo2(q.p2) };                 \
      Hq qv = { hi2(q.m2), hi2(q.m1), hi2(q.p1), hi2(q.p2) };                 \
      f2 lU, cU, lV, cV;                                                      \
      evalp7(Y2u[((c)+2)&7], Y2u[((c)+3)&7], Y2u[((c)+4)&7], Y2u[((c)+5)&7],  \
             Y2u[((c)+6)&7], Y2u[((c)+7)&7], Y2u[(c)&7], qu, lU, cU);         \
      evalp7(Y2v[((c)+2)&7], Y2v[((c)+3)&7], Y2v[((c)+4)&7], Y2v[((c)+5)&7],  \
             Y2v[((c)+6)&7], Y2v[((c)+7)&7], Y2v[(c)&7], qv, lV, cV);         \
      f2 uv2 = cU * cV * cV;                                                  \
      f2 kU = pfma(mu_u, lU, pfma(NA, uv2, pfma(-ff, cU, sp(ff))));           \
      f2 kV = pfma(mu_v, lV, pfma(NB, uv2, sp(-kpf) * cV));                   \
      Y3u[(c)&7] = pfma(0.5f, kU, Du[((c)+4)&7]);   /* u0 lag 9 */            \
      Y3v[(c)&7] = pfma(0.5f, kV, Dv[((c)+4)&7]);                             \
      S[3][(c)&3][tid] = cat(Y3u[((c)+7)&7], Y3v[((c)+7)&7]);                 \
    }                                                                         \
    if (G4) { /* k4 on Y3, row yL-12 ; write output */                        \
      Hq4 q = rdq4(&S[3][((c)+2)&3][0], xm2, xm1, xp1, xp2);                  \
      Hq qu = { lo2(q.m2), lo2(q.m1), lo2(q.p1), lo2(q.p2) };                 \
      Hq qv = { hi2(q.m2), hi2(q.m1), hi2(q.p1), hi2(q.p2) };                 \
      f2 lU, cU4, lV, cV4;                                                    \
      evalp7(Y3u[((c)+2)&7], Y3u[((c)+3)&7], Y3u[((c)+4)&7], Y3u[((c)+5)&7],  \
             Y3u[((c)+6)&7], Y3u[((c)+7)&7], Y3u[(c)&7], qu, lU, cU4);        \
      evalp7(Y3v[((c)+2)&7], Y3v[((c)+3)&7], Y3v[((c)+4)&7], Y3v[((c)+5)&7],  \
             Y3v[((c)+6)&7], Y3v[((c)+7)&7], Y3v[(c)&7], qv, lV, cV4);        \
      f2 uv2 = cU4 * cV4 * cV4;                                               \
      f2 kU = pfma(mu_u, lU, pfma(NA, uv2, pfma(-ff, cU4, sp(ff))));          \
      f2 kV = pfma(mu_v, lV, pfma(NB, uv2, sp(-kpf) * cV4));                  \
      f2 sU = pfma(4.0f, cU4, kU) + ACu[((c)+2)&7];   /* AC lag 6 */          \
      f2 sV = pfma(4.0f, cV4, kV) + ACv[((c)+2)&7];                           \
      f2 oUq = sp(1.0f / 12.0f) * sU;                                         \
      f2 oVq = sp(1.0f / 12.0f) * sV;                                         \
      int yS = Y0 + t_ - 24;                                                  \
      *(f2*)(oU + (size_t)yS * 1024) = oUq;                                   \
      *(f2*)(oV + (size_t)yS * 1024) = oVq;                                   \
    }                                                                         \
    if ((c) & 1) {                                                            \
      asm volatile("s_waitcnt lgkmcnt(0)" ::: "memory");                      \
      __builtin_amdgcn_s_barrier();                                           \
    }                                                                         \
  }

    // warmup: compile-time guards per 8-step block
    STEP(0,0,0,0,0, 0) STEP(1,0,0,0,0, 0) STEP(2,0,0,0,0, 0) STEP(3,0,0,0,0, 0)
    STEP(4,0,0,0,0, 0) STEP(5,0,0,0,0, 0) STEP(6,1,0,0,0, 0) STEP(7,1,0,0,0, 0)

    STEP(0,1,0,0,0, 8) STEP(1,1,0,0,0, 8) STEP(2,1,0,0,0, 8) STEP(3,1,0,0,0, 8)
    STEP(4,1,1,0,0, 8) STEP(5,1,1,0,0, 8) STEP(6,1,1,0,0, 8) STEP(7,1,1,0,0, 8)

    STEP(0,1,1,0,0,16) STEP(1,1,1,0,0,16) STEP(2,1,1,1,0,16) STEP(3,1,1,1,0,16)
    STEP(4,1,1,1,0,16) STEP(5,1,1,1,0,16) STEP(6,1,1,1,0,16) STEP(7,1,1,1,0,16)

    #pragma unroll 1
    for (int tb = 24; tb < STEPS; tb += 8) {
        STEP(0,1,1,1,1,tb) STEP(1,1,1,1,1,tb) STEP(2,1,1,1,1,tb) STEP(3,1,1,1,1,tb)
        STEP(4,1,1,1,1,tb) STEP(5,1,1,1,1,tb) STEP(6,1,1,1,1,tb) STEP(7,1,1,1,1,tb)
    }
#undef STEP
}

extern "C" void kernel_launch(void* const* d_in, const int* in_sizes, int n_in,
                              void* d_out, int out_size, void* d_ws, size_t ws_size,
                              hipStream_t stream) {
    const float* h   = (const float*)d_in[0];
    const float* pCA = (const float*)d_in[1];
    const float* pCB = (const float*)d_in[2];
    const float* pNA = (const float*)d_in[3];
    const float* pNB = (const float*)d_in[4];
    const float* pf  = (const float*)d_in[5];
    const float* pk  = (const float*)d_in[6];
    float* outp = (float*)d_out;

    dim3 grid(1024 / HROWS, 1, 16);   // 16 strips x 16 batches = 256 blocks
    dim3 block(NT);
    rcnn_rk4_march<<<grid, block, 0, stream>>>(h, pCA, pCB, pNA, pNB, pf, pk, outp);
}